// Round 2
// baseline (12819.556 us; speedup 1.0000x reference)
//
#include <hip/hip_runtime.h>
#include <hip/hip_bf16.h>
#include <stdint.h>

typedef unsigned short u16;
typedef unsigned int   u32;
typedef __attribute__((ext_vector_type(4))) float f32x4;
typedef __attribute__((ext_vector_type(8))) short bf16x8;

static __device__ __forceinline__ u16 f2bf(float x) {
  union { float f; u32 u; } v; v.f = x;
  u32 r = v.u + 0x7FFFu + ((v.u >> 16) & 1u);
  return (u16)(r >> 16);
}
static __device__ __forceinline__ float bf2f(u16 b) {
  union { u32 u; float f; } v; v.u = ((u32)b) << 16;
  return v.f;
}

// ---------------- small prep kernels ----------------

__global__ void split_hl(const float* __restrict__ in, u16* __restrict__ hi,
                         u16* __restrict__ lo, int n) {
  int i = blockIdx.x * 256 + threadIdx.x;
  if (i < n) {
    float v = in[i];
    u16 h = f2bf(v);
    hi[i] = h;
    lo[i] = f2bf(v - bf2f(h));
  }
}

__global__ void embed_split(const int* __restrict__ x, const float* __restrict__ emb,
                            u16* __restrict__ hi, u16* __restrict__ lo) {
  int gid = blockIdx.x * 256 + threadIdx.x;   // 4096*512 total
  int bt = gid >> 9, d = gid & 511;
  float v = emb[(size_t)x[bt] * 512 + d];
  u16 h = f2bf(v);
  hi[gid] = h;
  lo[gid] = f2bf(v - bf2f(h));
}

// Pack Whh into per-lane MFMA B-fragment order, hi/lo bf16 split.
// flat tid = ((((((lyr*2+d)*16+W)*4+g)*8+kt)*2+pass)*64+lane)*4+dw
// weight row = g*256 + W*16 + (lane&15), k = kt*32 + (lane>>4)*8 + dw*2
__global__ void lstm_wpack(const float* __restrict__ Whh, u32* __restrict__ wp) {
  int tid = blockIdx.x * 256 + threadIdx.x;   // 1,048,576 total
  int dw   = tid & 3;
  int lane = (tid >> 2) & 63;
  int pass = (tid >> 8) & 1;
  int kt   = (tid >> 9) & 7;
  int g    = (tid >> 12) & 3;
  int W    = (tid >> 14) & 15;
  int d    = (tid >> 18) & 1;
  int lyr  = (tid >> 19) & 1;
  int row = g * 256 + W * 16 + (lane & 15);
  int k   = kt * 32 + (lane >> 4) * 8 + dw * 2;
  const float* src = Whh + (((size_t)(lyr * 2 + d) * 1024 + row) * 256);
  float w0 = src[k], w1 = src[k + 1];
  u16 h0 = f2bf(w0), h1 = f2bf(w1);
  u32 out;
  if (pass == 0) out = (u32)h0 | ((u32)h1 << 16);
  else {
    u16 l0 = f2bf(w0 - bf2f(h0)), l1 = f2bf(w1 - bf2f(h1));
    out = (u32)l0 | ((u32)l1 << 16);
  }
  wp[tid] = out;
}

__global__ void resadd_split(const float* __restrict__ a, const float* __restrict__ b,
                             u16* __restrict__ hi, u16* __restrict__ lo, int n) {
  int i = blockIdx.x * 256 + threadIdx.x;
  if (i < n) {
    float v = a[i] + b[i];
    u16 h = f2bf(v);
    hi[i] = h;
    lo[i] = f2bf(v - bf2f(h));
  }
}

// ---------------- bf16x3 MFMA GEMM: C = A * B^T + bias ----------------
// A: M x K (row-major, hi/lo bf16), B: N x K (row-major weights, hi/lo bf16)
// XSWZ: write C in the lstm per-lane fragment order instead of row-major.
template<int RELU, int WF32, int WHL, int XSWZ>
__global__ __launch_bounds__(256) void gemm_x3(
    const u16* __restrict__ Ahi, const u16* __restrict__ Alo,
    const u16* __restrict__ Bhi, const u16* __restrict__ Blo,
    const float* __restrict__ bias,
    float* __restrict__ Cf, u16* __restrict__ Chi, u16* __restrict__ Clo,
    int M, int N, int Kd)
{
  __shared__ u16 As_hi[128][40], As_lo[128][40], Bs_hi[128][40], Bs_lo[128][40];
  int t = threadIdx.x;
  int bm = blockIdx.x * 128, bn = blockIdx.y * 128;
  int l = t & 63, wid = t >> 6;
  int wy = wid >> 1, wx = wid & 1;
  f32x4 acc[4][4];
#pragma unroll
  for (int i = 0; i < 4; i++)
#pragma unroll
    for (int j = 0; j < 4; j++) acc[i][j] = (f32x4){0.f, 0.f, 0.f, 0.f};

  for (int kt = 0; kt < Kd; kt += 32) {
    __syncthreads();
#pragma unroll
    for (int cc = 0; cc < 2; cc++) {
      int c = t + cc * 256;
      int row = c >> 2, k8 = (c & 3) << 3;
      *(uint4*)&As_hi[row][k8] = *(const uint4*)(Ahi + (size_t)(bm + row) * Kd + kt + k8);
      *(uint4*)&As_lo[row][k8] = *(const uint4*)(Alo + (size_t)(bm + row) * Kd + kt + k8);
      *(uint4*)&Bs_hi[row][k8] = *(const uint4*)(Bhi + (size_t)(bn + row) * Kd + kt + k8);
      *(uint4*)&Bs_lo[row][k8] = *(const uint4*)(Blo + (size_t)(bn + row) * Kd + kt + k8);
    }
    __syncthreads();
    bf16x8 bh[4], bl[4];
    int k8 = (l >> 4) << 3;
#pragma unroll
    for (int ni = 0; ni < 4; ni++) {
      int r = wx * 64 + ni * 16 + (l & 15);
      bh[ni] = *(const bf16x8*)&Bs_hi[r][k8];
      bl[ni] = *(const bf16x8*)&Bs_lo[r][k8];
    }
#pragma unroll
    for (int mi = 0; mi < 4; mi++) {
      int r = wy * 64 + mi * 16 + (l & 15);
      bf16x8 ah = *(const bf16x8*)&As_hi[r][k8];
      bf16x8 al = *(const bf16x8*)&As_lo[r][k8];
#pragma unroll
      for (int ni = 0; ni < 4; ni++) {
        acc[mi][ni] = __builtin_amdgcn_mfma_f32_16x16x32_bf16(ah, bh[ni], acc[mi][ni], 0, 0, 0);
        acc[mi][ni] = __builtin_amdgcn_mfma_f32_16x16x32_bf16(ah, bl[ni], acc[mi][ni], 0, 0, 0);
        acc[mi][ni] = __builtin_amdgcn_mfma_f32_16x16x32_bf16(al, bh[ni], acc[mi][ni], 0, 0, 0);
      }
    }
  }
#pragma unroll
  for (int ni = 0; ni < 4; ni++) {
    int col = bn + wx * 64 + ni * 16 + (l & 15);
    float bv = bias ? bias[col] : 0.f;
#pragma unroll
    for (int mi = 0; mi < 4; mi++) {
#pragma unroll
      for (int r = 0; r < 4; r++) {
        int row = bm + wy * 64 + mi * 16 + (l >> 4) * 4 + r;
        float v = acc[mi][ni][r] + bv;
        if (RELU) v = fmaxf(v, 0.f);
        if (XSWZ) {
          // row = b*256 + t (bt index), col = gate-row (g*256 + W*16 + u)
          int tt = row & 255, b = row >> 8;
          int g = col >> 8, c8 = col & 255;
          int Wv = c8 >> 4, uu = c8 & 15;
          int lane = ((b >> 2) << 4) | uu;
          size_t o = ((((size_t)tt * 16 + Wv) * 4 + g) * 64 + lane) * 4 + (b & 3);
          Cf[o] = v;
        } else {
          size_t o = (size_t)row * N + col;
          if (WF32) Cf[o] = v;
          if (WHL) { u16 h = f2bf(v); Chi[o] = h; Clo[o] = f2bf(v - bf2f(h)); }
        }
      }
    }
  }
}

// ---------------- LSTM recurrence: one workgroup per direction ----------------
// 1024 threads = 16 waves. Wave W owns all 4 gates of units [W*16, W*16+16).
// Whh resident in VGPRs (256/lane: 4 gates x 8 kt x hi/lo bf16x8 B-frags).
// h exchanged via LDS double buffer, ONE __syncthreads per step.
// xw pre-swizzled to per-lane fragment order (see gemm XSWZ epilogue).
__global__ __launch_bounds__(1024, 1) void lstm_rec2(
    const u32* __restrict__ wpack_l,
    const float* __restrict__ xwsw_f, const float* __restrict__ xwsw_b,
    u16* __restrict__ out_hi, u16* __restrict__ out_lo, float* __restrict__ out_f)
{
  int dir = blockIdx.x;
  int tid = threadIdx.x;
  int W = tid >> 6, l = tid & 63;
  int bb  = l & 15;          // A-frag row (batch) for LDS reads
  int mb  = (l >> 4) * 4;    // C-frag batch base
  int wu  = W * 16 + (l & 15); // unit this lane produces
  const float* xw = dir ? xwsw_b : xwsw_f;

  // resident weight fragments: wf[g][kt][pass]
  bf16x8 wf[4][8][2];
#pragma unroll
  for (int g = 0; g < 4; g++) {
    const u32* wb = wpack_l + (size_t)((dir * 16 + W) * 4 + g) * 4096;
#pragma unroll
    for (int kt = 0; kt < 8; kt++)
#pragma unroll
      for (int p = 0; p < 2; p++)
        wf[g][kt][p] = *(const bf16x8*)(const void*)(wb + ((kt * 2 + p) * 64 + l) * 4);
  }

  // h double buffer, [buf][batch][unit] with XOR-swizzled 8-unit blocks
  __shared__ u16 hH[2][16][256];
  __shared__ u16 hL[2][16][256];

  f32x4 cst = (f32x4){0.f, 0.f, 0.f, 0.f};

  for (int s = 0; s < 256; s++) {
    int tpos = dir ? (255 - s) : s;
    int cb = s & 1, pb = cb ^ 1;

    // xw fragment loads (independent of h; latency hides under MFMA)
    const float* xb = xw + ((size_t)tpos * 16 + W) * 1024;
    f32x4 xwv[4];
#pragma unroll
    for (int g = 0; g < 4; g++)
      xwv[g] = *(const f32x4*)(xb + g * 256 + l * 4);

    f32x4 acc[4];
#pragma unroll
    for (int g = 0; g < 4; g++) acc[g] = (f32x4){0.f, 0.f, 0.f, 0.f};

    if (s > 0) {
#pragma unroll
      for (int kt = 0; kt < 8; kt++) {
        int bx = (((kt * 4 + (l >> 4)) ^ (bb & 7)) << 3);
        bf16x8 ah = *(const bf16x8*)&hH[pb][bb][bx];
        bf16x8 al = *(const bf16x8*)&hL[pb][bb][bx];
#pragma unroll
        for (int g = 0; g < 4; g++)
          acc[g] = __builtin_amdgcn_mfma_f32_16x16x32_bf16(ah, wf[g][kt][0], acc[g], 0, 0, 0);
#pragma unroll
        for (int g = 0; g < 4; g++)
          acc[g] = __builtin_amdgcn_mfma_f32_16x16x32_bf16(ah, wf[g][kt][1], acc[g], 0, 0, 0);
#pragma unroll
        for (int g = 0; g < 4; g++)
          acc[g] = __builtin_amdgcn_mfma_f32_16x16x32_bf16(al, wf[g][kt][0], acc[g], 0, 0, 0);
      }
    }

    // gates fully in registers: lane has all 4 gates for unit wu, batches mb..mb+3
#pragma unroll
    for (int r = 0; r < 4; r++) {
      float gi = acc[0][r] + xwv[0][r];
      float gf = acc[1][r] + xwv[1][r];
      float gg = acc[2][r] + xwv[2][r];
      float go = acc[3][r] + xwv[3][r];
      float si = 1.f / (1.f + __expf(-gi));
      float sf = 1.f / (1.f + __expf(-gf));
      float so = 1.f / (1.f + __expf(-go));
      float tg = 1.f - 2.f / (__expf(2.f * gg) + 1.f);
      float c = sf * cst[r] + si * tg;
      cst[r] = c;
      float th = 1.f - 2.f / (__expf(2.f * c) + 1.f);
      float h = so * th;

      u16 hb = f2bf(h);
      u16 lb = f2bf(h - bf2f(hb));
      int b = mb + r;
      int idx = ((((wu >> 3) ^ (b & 7)) << 3)) + (wu & 7);
      hH[cb][b][idx] = hb;
      hL[cb][b][idx] = lb;
      size_t oo = (((size_t)b * 256 + tpos) * 512) + dir * 256 + wu;
      out_hi[oo] = hb;
      out_lo[oo] = lb;
      if (out_f) out_f[oo] = h;
    }
    __syncthreads();
  }
}

// ---------------- final small GEMM (fp32 exact): em = h256 * out_W^T + out_b
__global__ __launch_bounds__(256) void out_gemm(const float* __restrict__ h,
                                                const float* __restrict__ Wo,
                                                const float* __restrict__ bo,
                                                float* __restrict__ em)
{
  int t = threadIdx.x;
  if (t >= 160) return;
  int r = t / 20, j = t - r * 20;
  int bt = blockIdx.x * 8 + r;
  const float* hr = h + (size_t)bt * 256;
  const float* wr = Wo + j * 256;
  float acc = 0.f;
#pragma unroll 4
  for (int k = 0; k < 256; k++) acc += hr[k] * wr[k];
  em[(size_t)bt * 20 + j] = acc + bo[j];
}

// ---------------- Viterbi ----------------
__global__ __launch_bounds__(192) void viterbi(const float* __restrict__ em,
                                               const float* __restrict__ cstart,
                                               const float* __restrict__ cend,
                                               const float* __restrict__ ctrans,
                                               float* __restrict__ tago)
{
  __shared__ float sc[8][20];
  __shared__ float tl[400];
  __shared__ unsigned char hist[255][8][20];
  int t = threadIdx.x;
  for (int i = t; i < 400; i += 192) tl[i] = ctrans[i];
  int bl = t / 20, j = t - bl * 20;
  bool act = (t < 160);
  int b = blockIdx.x * 8 + bl;
  if (act) sc[bl][j] = cstart[j] + em[((size_t)b * 256) * 20 + j];
  __syncthreads();
  for (int step = 1; step < 256; step++) {
    float best = -1e30f; int bi = 0;
    if (act) {
      best = sc[bl][0] + tl[j]; bi = 0;
#pragma unroll
      for (int i = 1; i < 20; i++) {
        float v = sc[bl][i] + tl[i * 20 + j];
        if (v > best) { best = v; bi = i; }
      }
      hist[step - 1][bl][j] = (unsigned char)bi;
    }
    __syncthreads();
    if (act) sc[bl][j] = best + em[((size_t)b * 256 + step) * 20 + j];
    __syncthreads();
  }
  if (act && j == 0) {
    float best = sc[bl][0] + cend[0]; int bj = 0;
    for (int i = 1; i < 20; i++) {
      float v = sc[bl][i] + cend[i];
      if (v > best) { best = v; bj = i; }
    }
    int tag = bj;
    tago[(size_t)b * 256 + 255] = (float)tag;
    for (int step = 254; step >= 0; step--) {
      tag = hist[step][bl][tag];
      tago[(size_t)b * 256 + step] = (float)tag;
    }
  }
}

// ---------------- launch ----------------
extern "C" void kernel_launch(void* const* d_in, const int* in_sizes, int n_in,
                              void* d_out, int out_size, void* d_ws, size_t ws_size,
                              hipStream_t stream)
{
  const int*   x   = (const int*)  d_in[0];
  const float* emb = (const float*)d_in[1];
  const float* Wih = (const float*)d_in[2];
  const float* Whh = (const float*)d_in[3];
  const float* lb  = (const float*)d_in[4];
  const float* fW1 = (const float*)d_in[5];
  const float* fb1 = (const float*)d_in[6];
  const float* fW2 = (const float*)d_in[7];
  const float* fb2 = (const float*)d_in[8];
  const float* foW = (const float*)d_in[9];
  const float* fob = (const float*)d_in[10];
  const float* oW  = (const float*)d_in[11];
  const float* ob  = (const float*)d_in[12];
  const float* cst = (const float*)d_in[13];
  const float* cen = (const float*)d_in[14];
  const float* ctr = (const float*)d_in[15];

  const size_t MB = 1u << 20;
  if (ws_size < 100 * MB) return;
  char* ws = (char*)d_ws;

  u16* embHi = (u16*)(ws + 0 * MB);
  u16* embLo = (u16*)(ws + 4 * MB);
  u16* l1Hi  = (u16*)(ws + 8 * MB);
  u16* l1Lo  = (u16*)(ws + 12 * MB);
  float* l2F = (float*)(ws + 16 * MB);
  u16* l2Hi  = (u16*)(ws + 24 * MB);
  u16* l2Lo  = (u16*)(ws + 28 * MB);
  float* xwF = (float*)(ws + 32 * MB);   // swizzled xw fwd (16 MB)
  float* xwB = (float*)(ws + 48 * MB);   // swizzled xw bwd (16 MB)
  u32* wpck  = (u32*)(ws + 80 * MB);     // 4 MB
  u16* wihHi = (u16*)(ws + 84 * MB);
  u16* wihLo = (u16*)(ws + 88 * MB);
  u16* fw1Hi = (u16*)(ws + 92 * MB);
  u16* fw1Lo = (u16*)(ws + 93 * MB);
  u16* fw2Hi = (u16*)(ws + 94 * MB);
  u16* fw2Lo = (u16*)(ws + 95 * MB);
  u16* ffoHi = (u16*)(ws + 96 * MB);
  u16* ffoLo = (u16*)(ws + 96 * MB + 512 * 1024);
  // aliases into xw regions (free after the recurrent layers)
  u16* t1Hi = (u16*)xwF;
  u16* t1Lo = (u16*)((char*)xwF + 4 * MB);
  u16* t2Hi = (u16*)xwB;
  u16* t2Lo = (u16*)((char*)xwB + 4 * MB);
  float* h2F = (float*)((char*)xwB + 8 * MB);
  u16* sumHi = (u16*)((char*)xwF + 8 * MB);
  u16* sumLo = (u16*)((char*)xwF + 12 * MB);
  float* h256F = (float*)xwF;

  float* em   = (float*)d_out;
  float* tago = (float*)d_out + 81920;

  dim3 blk(256);

  // weight prep
  split_hl<<<8192, blk, 0, stream>>>(Wih, wihHi, wihLo, 4 * 1024 * 512);
  split_hl<<<2048, blk, 0, stream>>>(fW1, fw1Hi, fw1Lo, 2 * 512 * 512);
  split_hl<<<2048, blk, 0, stream>>>(fW2, fw2Hi, fw2Lo, 2 * 512 * 512);
  split_hl<<<512,  blk, 0, stream>>>(foW, ffoHi, ffoLo, 256 * 512);
  lstm_wpack<<<4096, blk, 0, stream>>>(Whh, wpck);
  embed_split<<<8192, blk, 0, stream>>>(x, emb, embHi, embLo);

  // layer 0: xw GEMMs (write swizzled), then recurrence (2 CUs, LDS-synced)
  gemm_x3<0,1,0,1><<<dim3(32, 8), blk, 0, stream>>>(embHi, embLo,
      wihHi + 0 * 524288, wihLo + 0 * 524288, lb + 0 * 1024,
      xwF, nullptr, nullptr, 4096, 1024, 512);
  gemm_x3<0,1,0,1><<<dim3(32, 8), blk, 0, stream>>>(embHi, embLo,
      wihHi + 1 * 524288, wihLo + 1 * 524288, lb + 1 * 1024,
      xwB, nullptr, nullptr, 4096, 1024, 512);
  lstm_rec2<<<2, dim3(1024), 0, stream>>>(wpck, xwF, xwB, l1Hi, l1Lo, nullptr);

  // layer 1
  gemm_x3<0,1,0,1><<<dim3(32, 8), blk, 0, stream>>>(l1Hi, l1Lo,
      wihHi + 2 * 524288, wihLo + 2 * 524288, lb + 2 * 1024,
      xwF, nullptr, nullptr, 4096, 1024, 512);
  gemm_x3<0,1,0,1><<<dim3(32, 8), blk, 0, stream>>>(l1Hi, l1Lo,
      wihHi + 3 * 524288, wihLo + 3 * 524288, lb + 3 * 1024,
      xwB, nullptr, nullptr, 4096, 1024, 512);
  lstm_rec2<<<2, dim3(1024), 0, stream>>>(wpck + (1u << 19), xwF, xwB,
      l2Hi, l2Lo, l2F);

  // FF stack
  gemm_x3<1,0,1,0><<<dim3(32, 4), blk, 0, stream>>>(l2Hi, l2Lo,
      fw1Hi + 0, fw1Lo + 0, fb1 + 0, nullptr, t1Hi, t1Lo, 4096, 512, 512);
  gemm_x3<0,0,1,0><<<dim3(32, 4), blk, 0, stream>>>(t1Hi, t1Lo,
      fw2Hi + 0, fw2Lo + 0, fb2 + 0, nullptr, t2Hi, t2Lo, 4096, 512, 512);
  gemm_x3<1,0,1,0><<<dim3(32, 4), blk, 0, stream>>>(t2Hi, t2Lo,
      fw1Hi + 262144, fw1Lo + 262144, fb1 + 512, nullptr, t1Hi, t1Lo, 4096, 512, 512);
  gemm_x3<0,1,0,0><<<dim3(32, 4), blk, 0, stream>>>(t1Hi, t1Lo,
      fw2Hi + 262144, fw2Lo + 262144, fb2 + 512, h2F, nullptr, nullptr, 4096, 512, 512);
  resadd_split<<<8192, blk, 0, stream>>>(h2F, l2F, sumHi, sumLo, 4096 * 512);
  gemm_x3<0,1,0,0><<<dim3(32, 2), blk, 0, stream>>>(sumHi, sumLo,
      ffoHi, ffoLo, fob, h256F, nullptr, nullptr, 4096, 256, 512);

  out_gemm<<<512, blk, 0, stream>>>(h256F, oW, ob, em);
  viterbi<<<2, dim3(192), 0, stream>>>(em, cst, cen, ctr, tago);
}

// Round 3
// 6235.641 us; speedup vs baseline: 2.0559x; 2.0559x over previous
//
#include <hip/hip_runtime.h>
#include <hip/hip_bf16.h>
#include <stdint.h>

typedef unsigned short u16;
typedef unsigned int   u32;
typedef __attribute__((ext_vector_type(4))) float f32x4;
typedef __attribute__((ext_vector_type(8))) short bf16x8;

static __device__ __forceinline__ u16 f2bf(float x) {
  union { float f; u32 u; } v; v.f = x;
  u32 r = v.u + 0x7FFFu + ((v.u >> 16) & 1u);
  return (u16)(r >> 16);
}
static __device__ __forceinline__ float bf2f(u16 b) {
  union { u32 u; float f; } v; v.u = ((u32)b) << 16;
  return v.f;
}

// ---------------- small prep kernels ----------------

__global__ void split_hl(const float* __restrict__ in, u16* __restrict__ hi,
                         u16* __restrict__ lo, int n) {
  int i = blockIdx.x * 256 + threadIdx.x;
  if (i < n) {
    float v = in[i];
    u16 h = f2bf(v);
    hi[i] = h;
    lo[i] = f2bf(v - bf2f(h));
  }
}

__global__ void embed_split(const int* __restrict__ x, const float* __restrict__ emb,
                            u16* __restrict__ hi, u16* __restrict__ lo) {
  int gid = blockIdx.x * 256 + threadIdx.x;   // 4096*512 total
  int bt = gid >> 9, d = gid & 511;
  float v = emb[(size_t)x[bt] * 512 + d];
  u16 h = f2bf(v);
  hi[gid] = h;
  lo[gid] = f2bf(v - bf2f(h));
}

// Pack Whh into per-lane MFMA B-fragment order, single bf16 (hi only).
// flat tid = (((((lyr*2+d)*16+W)*4+g)*8+kt)*64+lane)*4+dw   (524,288 total)
// weight row = g*256 + W*16 + (lane&15), k = kt*32 + (lane>>4)*8 + dw*2
__global__ void lstm_wpack(const float* __restrict__ Whh, u32* __restrict__ wp) {
  int tid = blockIdx.x * 256 + threadIdx.x;
  int dw   = tid & 3;
  int lane = (tid >> 2) & 63;
  int kt   = (tid >> 8) & 7;
  int g    = (tid >> 11) & 3;
  int W    = (tid >> 13) & 15;
  int d    = (tid >> 17) & 1;
  int lyr  = (tid >> 18) & 1;
  int row = g * 256 + W * 16 + (lane & 15);
  int k   = kt * 32 + (lane >> 4) * 8 + dw * 2;
  const float* src = Whh + (((size_t)(lyr * 2 + d) * 1024 + row) * 256);
  u16 h0 = f2bf(src[k]), h1 = f2bf(src[k + 1]);
  wp[tid] = (u32)h0 | ((u32)h1 << 16);
}

__global__ void resadd_split(const float* __restrict__ a, const float* __restrict__ b,
                             u16* __restrict__ hi, u16* __restrict__ lo, int n) {
  int i = blockIdx.x * 256 + threadIdx.x;
  if (i < n) {
    float v = a[i] + b[i];
    u16 h = f2bf(v);
    hi[i] = h;
    lo[i] = f2bf(v - bf2f(h));
  }
}

// ---------------- bf16 MFMA GEMM: C = A * B^T + bias ----------------
// A: M x K (row-major, hi/lo bf16), B: N x K (row-major weights, bf16 hi [+lo if BLO])
// Passes: AhBh + AlBh (+ AhBl if BLO). XSWZ: write C in lstm per-lane frag order.
template<int RELU, int WF32, int WHL, int XSWZ, int BLO>
__global__ __launch_bounds__(256) void gemm_x3(
    const u16* __restrict__ Ahi, const u16* __restrict__ Alo,
    const u16* __restrict__ Bhi, const u16* __restrict__ Blo,
    const float* __restrict__ bias,
    float* __restrict__ Cf, u16* __restrict__ Chi, u16* __restrict__ Clo,
    int M, int N, int Kd)
{
  __shared__ u16 As_hi[128][40], As_lo[128][40], Bs_hi[128][40];
  __shared__ u16 Bs_lo[BLO ? 128 : 1][BLO ? 40 : 1];
  int t = threadIdx.x;
  int bm = blockIdx.x * 128, bn = blockIdx.y * 128;
  int l = t & 63, wid = t >> 6;
  int wy = wid >> 1, wx = wid & 1;
  f32x4 acc[4][4];
#pragma unroll
  for (int i = 0; i < 4; i++)
#pragma unroll
    for (int j = 0; j < 4; j++) acc[i][j] = (f32x4){0.f, 0.f, 0.f, 0.f};

  for (int kt = 0; kt < Kd; kt += 32) {
    __syncthreads();
#pragma unroll
    for (int cc = 0; cc < 2; cc++) {
      int c = t + cc * 256;
      int row = c >> 2, k8 = (c & 3) << 3;
      *(uint4*)&As_hi[row][k8] = *(const uint4*)(Ahi + (size_t)(bm + row) * Kd + kt + k8);
      *(uint4*)&As_lo[row][k8] = *(const uint4*)(Alo + (size_t)(bm + row) * Kd + kt + k8);
      *(uint4*)&Bs_hi[row][k8] = *(const uint4*)(Bhi + (size_t)(bn + row) * Kd + kt + k8);
      if (BLO)
        *(uint4*)&Bs_lo[row][k8] = *(const uint4*)(Blo + (size_t)(bn + row) * Kd + kt + k8);
    }
    __syncthreads();
    bf16x8 bh[4], bl[4];
    int k8 = (l >> 4) << 3;
#pragma unroll
    for (int ni = 0; ni < 4; ni++) {
      int r = wx * 64 + ni * 16 + (l & 15);
      bh[ni] = *(const bf16x8*)&Bs_hi[r][k8];
      if (BLO) bl[ni] = *(const bf16x8*)&Bs_lo[r][k8];
    }
#pragma unroll
    for (int mi = 0; mi < 4; mi++) {
      int r = wy * 64 + mi * 16 + (l & 15);
      bf16x8 ah = *(const bf16x8*)&As_hi[r][k8];
      bf16x8 al = *(const bf16x8*)&As_lo[r][k8];
#pragma unroll
      for (int ni = 0; ni < 4; ni++) {
        acc[mi][ni] = __builtin_amdgcn_mfma_f32_16x16x32_bf16(ah, bh[ni], acc[mi][ni], 0, 0, 0);
        acc[mi][ni] = __builtin_amdgcn_mfma_f32_16x16x32_bf16(al, bh[ni], acc[mi][ni], 0, 0, 0);
        if (BLO)
          acc[mi][ni] = __builtin_amdgcn_mfma_f32_16x16x32_bf16(ah, bl[ni], acc[mi][ni], 0, 0, 0);
      }
    }
  }
#pragma unroll
  for (int ni = 0; ni < 4; ni++) {
    int col = bn + wx * 64 + ni * 16 + (l & 15);
    float bv = bias ? bias[col] : 0.f;
#pragma unroll
    for (int mi = 0; mi < 4; mi++) {
#pragma unroll
      for (int r = 0; r < 4; r++) {
        int row = bm + wy * 64 + mi * 16 + (l >> 4) * 4 + r;
        float v = acc[mi][ni][r] + bv;
        if (RELU) v = fmaxf(v, 0.f);
        if (XSWZ) {
          // row = b*256 + t (bt index), col = gate-row (g*256 + W*16 + u)
          int tt = row & 255, b = row >> 8;
          int g = col >> 8, c8 = col & 255;
          int Wv = c8 >> 4, uu = c8 & 15;
          int lane = ((b >> 2) << 4) | uu;
          size_t o = ((((size_t)tt * 16 + Wv) * 4 + g) * 64 + lane) * 4 + (b & 3);
          Cf[o] = v;
        } else {
          size_t o = (size_t)row * N + col;
          if (WF32) Cf[o] = v;
          if (WHL) { u16 h = f2bf(v); Chi[o] = h; Clo[o] = f2bf(v - bf2f(h)); }
        }
      }
    }
  }
}

// ---------------- LSTM recurrence: one workgroup per direction ----------------
// 1024 threads = 16 waves. Wave W owns all 4 gates of units [W*16, W*16+16).
// Whh resident in VGPRs as SINGLE bf16 (wf[4][8] = 128 VGPRs -> fits v0-v255;
// the round-2 hi/lo version needed 256+ and spilled to scratch).
// h exchanged via LDS double buffer (single bf16), ONE __syncthreads per step.
__global__ __launch_bounds__(1024, 1) void lstm_rec3(
    const u32* __restrict__ wpack_l,
    const float* __restrict__ xwsw_f, const float* __restrict__ xwsw_b,
    u16* __restrict__ out_hi, u16* __restrict__ out_lo, float* __restrict__ out_f)
{
  int dir = blockIdx.x;
  int tid = threadIdx.x;
  int W = tid >> 6, l = tid & 63;
  int bb  = l & 15;            // A-frag row (batch) for LDS reads
  int mb  = (l >> 4) * 4;      // C-frag batch base
  int wu  = W * 16 + (l & 15); // unit this lane produces
  const float* xw = dir ? xwsw_b : xwsw_f;

  // resident weight fragments: wf[g][kt]  (128 VGPRs)
  bf16x8 wf[4][8];
#pragma unroll
  for (int g = 0; g < 4; g++) {
    const u32* wb = wpack_l + (size_t)((dir * 16 + W) * 4 + g) * 2048;
#pragma unroll
    for (int kt = 0; kt < 8; kt++)
      wf[g][kt] = *(const bf16x8*)(const void*)(wb + (kt * 64 + l) * 4);
  }

  // h double buffer, [buf][batch][unit] with XOR-swizzled 8-unit blocks
  __shared__ u16 hH[2][16][256];

  f32x4 cst = (f32x4){0.f, 0.f, 0.f, 0.f};

  for (int s = 0; s < 256; s++) {
    int tpos = dir ? (255 - s) : s;
    int cb = s & 1, pb = cb ^ 1;

    // xw fragment loads (independent of h; L2/LLC-resident, hides under MFMA)
    const float* xb = xw + ((size_t)tpos * 16 + W) * 1024;
    f32x4 xwv[4];
#pragma unroll
    for (int g = 0; g < 4; g++)
      xwv[g] = *(const f32x4*)(xb + g * 256 + l * 4);

    f32x4 acc[4];
#pragma unroll
    for (int g = 0; g < 4; g++) acc[g] = (f32x4){0.f, 0.f, 0.f, 0.f};

    if (s > 0) {
#pragma unroll
      for (int kt = 0; kt < 8; kt++) {
        int bx = (((kt * 4 + (l >> 4)) ^ (bb & 7)) << 3);
        bf16x8 ah = *(const bf16x8*)&hH[pb][bb][bx];
#pragma unroll
        for (int g = 0; g < 4; g++)
          acc[g] = __builtin_amdgcn_mfma_f32_16x16x32_bf16(ah, wf[g][kt], acc[g], 0, 0, 0);
      }
    }

    // gates fully in registers: lane has all 4 gates for unit wu, batches mb..mb+3
#pragma unroll
    for (int r = 0; r < 4; r++) {
      float gi = acc[0][r] + xwv[0][r];
      float gf = acc[1][r] + xwv[1][r];
      float gg = acc[2][r] + xwv[2][r];
      float go = acc[3][r] + xwv[3][r];
      float si = 1.f / (1.f + __expf(-gi));
      float sf = 1.f / (1.f + __expf(-gf));
      float so = 1.f / (1.f + __expf(-go));
      float tg = 1.f - 2.f / (__expf(2.f * gg) + 1.f);
      float c = sf * cst[r] + si * tg;
      cst[r] = c;
      float th = 1.f - 2.f / (__expf(2.f * c) + 1.f);
      float h = so * th;

      u16 hb = f2bf(h);
      u16 lb = f2bf(h - bf2f(hb));
      int b = mb + r;
      int idx = ((((wu >> 3) ^ (b & 7)) << 3)) + (wu & 7);
      hH[cb][b][idx] = hb;
      size_t oo = (((size_t)b * 256 + tpos) * 512) + dir * 256 + wu;
      out_hi[oo] = hb;
      out_lo[oo] = lb;
      if (out_f) out_f[oo] = h;
    }
    __syncthreads();
  }
}

// ---------------- final small GEMM (fp32 exact): em = h256 * out_W^T + out_b
__global__ __launch_bounds__(256) void out_gemm(const float* __restrict__ h,
                                                const float* __restrict__ Wo,
                                                const float* __restrict__ bo,
                                                float* __restrict__ em)
{
  int t = threadIdx.x;
  if (t >= 160) return;
  int r = t / 20, j = t - r * 20;
  int bt = blockIdx.x * 8 + r;
  const float* hr = h + (size_t)bt * 256;
  const float* wr = Wo + j * 256;
  float acc = 0.f;
#pragma unroll 4
  for (int k = 0; k < 256; k++) acc += hr[k] * wr[k];
  em[(size_t)bt * 20 + j] = acc + bo[j];
}

// ---------------- Viterbi ----------------
__global__ __launch_bounds__(192) void viterbi(const float* __restrict__ em,
                                               const float* __restrict__ cstart,
                                               const float* __restrict__ cend,
                                               const float* __restrict__ ctrans,
                                               float* __restrict__ tago)
{
  __shared__ float sc[8][20];
  __shared__ float tl[400];
  __shared__ unsigned char hist[255][8][20];
  int t = threadIdx.x;
  for (int i = t; i < 400; i += 192) tl[i] = ctrans[i];
  int bl = t / 20, j = t - bl * 20;
  bool act = (t < 160);
  int b = blockIdx.x * 8 + bl;
  if (act) sc[bl][j] = cstart[j] + em[((size_t)b * 256) * 20 + j];
  __syncthreads();
  for (int step = 1; step < 256; step++) {
    float best = -1e30f; int bi = 0;
    if (act) {
      best = sc[bl][0] + tl[j]; bi = 0;
#pragma unroll
      for (int i = 1; i < 20; i++) {
        float v = sc[bl][i] + tl[i * 20 + j];
        if (v > best) { best = v; bi = i; }
      }
      hist[step - 1][bl][j] = (unsigned char)bi;
    }
    __syncthreads();
    if (act) sc[bl][j] = best + em[((size_t)b * 256 + step) * 20 + j];
    __syncthreads();
  }
  if (act && j == 0) {
    float best = sc[bl][0] + cend[0]; int bj = 0;
    for (int i = 1; i < 20; i++) {
      float v = sc[bl][i] + cend[i];
      if (v > best) { best = v; bj = i; }
    }
    int tag = bj;
    tago[(size_t)b * 256 + 255] = (float)tag;
    for (int step = 254; step >= 0; step--) {
      tag = hist[step][bl][tag];
      tago[(size_t)b * 256 + step] = (float)tag;
    }
  }
}

// ---------------- launch ----------------
extern "C" void kernel_launch(void* const* d_in, const int* in_sizes, int n_in,
                              void* d_out, int out_size, void* d_ws, size_t ws_size,
                              hipStream_t stream)
{
  const int*   x   = (const int*)  d_in[0];
  const float* emb = (const float*)d_in[1];
  const float* Wih = (const float*)d_in[2];
  const float* Whh = (const float*)d_in[3];
  const float* lb  = (const float*)d_in[4];
  const float* fW1 = (const float*)d_in[5];
  const float* fb1 = (const float*)d_in[6];
  const float* fW2 = (const float*)d_in[7];
  const float* fb2 = (const float*)d_in[8];
  const float* foW = (const float*)d_in[9];
  const float* fob = (const float*)d_in[10];
  const float* oW  = (const float*)d_in[11];
  const float* ob  = (const float*)d_in[12];
  const float* cst = (const float*)d_in[13];
  const float* cen = (const float*)d_in[14];
  const float* ctr = (const float*)d_in[15];

  const size_t MB = 1u << 20;
  if (ws_size < 100 * MB) return;
  char* ws = (char*)d_ws;

  u16* embHi = (u16*)(ws + 0 * MB);
  u16* embLo = (u16*)(ws + 4 * MB);
  u16* l1Hi  = (u16*)(ws + 8 * MB);
  u16* l1Lo  = (u16*)(ws + 12 * MB);
  float* l2F = (float*)(ws + 16 * MB);
  u16* l2Hi  = (u16*)(ws + 24 * MB);
  u16* l2Lo  = (u16*)(ws + 28 * MB);
  float* xwF = (float*)(ws + 32 * MB);   // swizzled xw fwd (16 MB)
  float* xwB = (float*)(ws + 48 * MB);   // swizzled xw bwd (16 MB)
  u32* wpck  = (u32*)(ws + 80 * MB);     // 2 MB (bf16-hi packed Whh)
  u16* wihHi = (u16*)(ws + 84 * MB);
  u16* wihLo = (u16*)(ws + 88 * MB);
  u16* fw1Hi = (u16*)(ws + 92 * MB);
  u16* fw1Lo = (u16*)(ws + 93 * MB);
  u16* fw2Hi = (u16*)(ws + 94 * MB);
  u16* fw2Lo = (u16*)(ws + 95 * MB);
  u16* ffoHi = (u16*)(ws + 96 * MB);
  u16* ffoLo = (u16*)(ws + 96 * MB + 512 * 1024);
  // aliases into xw regions (free after the recurrent layers)
  u16* t1Hi = (u16*)xwF;
  u16* t1Lo = (u16*)((char*)xwF + 4 * MB);
  u16* t2Hi = (u16*)xwB;
  u16* t2Lo = (u16*)((char*)xwB + 4 * MB);
  float* h2F = (float*)((char*)xwB + 8 * MB);
  u16* sumHi = (u16*)((char*)xwF + 8 * MB);
  u16* sumLo = (u16*)((char*)xwF + 12 * MB);
  float* h256F = (float*)xwF;

  float* em   = (float*)d_out;
  float* tago = (float*)d_out + 81920;

  dim3 blk(256);

  // weight prep
  split_hl<<<8192, blk, 0, stream>>>(Wih, wihHi, wihLo, 4 * 1024 * 512);
  split_hl<<<2048, blk, 0, stream>>>(fW1, fw1Hi, fw1Lo, 2 * 512 * 512);
  split_hl<<<2048, blk, 0, stream>>>(fW2, fw2Hi, fw2Lo, 2 * 512 * 512);
  split_hl<<<512,  blk, 0, stream>>>(foW, ffoHi, ffoLo, 256 * 512);
  lstm_wpack<<<2048, blk, 0, stream>>>(Whh, wpck);
  embed_split<<<8192, blk, 0, stream>>>(x, emb, embHi, embLo);

  // layer 0: xw GEMMs (write swizzled), then recurrence (2 CUs, LDS-synced)
  gemm_x3<0,1,0,1,0><<<dim3(32, 8), blk, 0, stream>>>(embHi, embLo,
      wihHi + 0 * 524288, wihLo + 0 * 524288, lb + 0 * 1024,
      xwF, nullptr, nullptr, 4096, 1024, 512);
  gemm_x3<0,1,0,1,0><<<dim3(32, 8), blk, 0, stream>>>(embHi, embLo,
      wihHi + 1 * 524288, wihLo + 1 * 524288, lb + 1 * 1024,
      xwB, nullptr, nullptr, 4096, 1024, 512);
  lstm_rec3<<<2, dim3(1024), 0, stream>>>(wpck, xwF, xwB, l1Hi, l1Lo, nullptr);

  // layer 1
  gemm_x3<0,1,0,1,0><<<dim3(32, 8), blk, 0, stream>>>(l1Hi, l1Lo,
      wihHi + 2 * 524288, wihLo + 2 * 524288, lb + 2 * 1024,
      xwF, nullptr, nullptr, 4096, 1024, 512);
  gemm_x3<0,1,0,1,0><<<dim3(32, 8), blk, 0, stream>>>(l1Hi, l1Lo,
      wihHi + 3 * 524288, wihLo + 3 * 524288, lb + 3 * 1024,
      xwB, nullptr, nullptr, 4096, 1024, 512);
  lstm_rec3<<<2, dim3(1024), 0, stream>>>(wpck + 262144, xwF, xwB,
      l2Hi, l2Lo, l2F);

  // FF stack
  gemm_x3<1,0,1,0,0><<<dim3(32, 4), blk, 0, stream>>>(l2Hi, l2Lo,
      fw1Hi + 0, fw1Lo + 0, fb1 + 0, nullptr, t1Hi, t1Lo, 4096, 512, 512);
  gemm_x3<0,0,1,0,0><<<dim3(32, 4), blk, 0, stream>>>(t1Hi, t1Lo,
      fw2Hi + 0, fw2Lo + 0, fb2 + 0, nullptr, t2Hi, t2Lo, 4096, 512, 512);
  gemm_x3<1,0,1,0,0><<<dim3(32, 4), blk, 0, stream>>>(t2Hi, t2Lo,
      fw1Hi + 262144, fw1Lo + 262144, fb1 + 512, nullptr, t1Hi, t1Lo, 4096, 512, 512);
  gemm_x3<0,1,0,0,0><<<dim3(32, 4), blk, 0, stream>>>(t1Hi, t1Lo,
      fw2Hi + 262144, fw2Lo + 262144, fb2 + 512, h2F, nullptr, nullptr, 4096, 512, 512);
  resadd_split<<<8192, blk, 0, stream>>>(h2F, l2F, sumHi, sumLo, 4096 * 512);
  gemm_x3<0,1,0,0,0><<<dim3(32, 2), blk, 0, stream>>>(sumHi, sumLo,
      ffoHi, ffoLo, fob, h256F, nullptr, nullptr, 4096, 256, 512);

  out_gemm<<<512, blk, 0, stream>>>(h256F, oW, ob, em);
  viterbi<<<2, dim3(192), 0, stream>>>(em, cst, cen, ctr, tago);
}

// Round 7
// 5446.163 us; speedup vs baseline: 2.3539x; 1.1450x over previous
//
#include <hip/hip_runtime.h>
#include <hip/hip_bf16.h>
#include <stdint.h>

typedef unsigned short u16;
typedef unsigned int   u32;
typedef __attribute__((ext_vector_type(4))) float f32x4;
typedef __attribute__((ext_vector_type(8))) short bf16x8;
typedef __attribute__((ext_vector_type(4))) unsigned short u16x4;

static __device__ __forceinline__ u16 f2bf(float x) {
  union { float f; u32 u; } v; v.f = x;
  u32 r = v.u + 0x7FFFu + ((v.u >> 16) & 1u);
  return (u16)(r >> 16);
}
static __device__ __forceinline__ float bf2f(u16 b) {
  union { u32 u; float f; } v; v.u = ((u32)b) << 16;
  return v.f;
}

// ---------------- small prep kernels ----------------

__global__ void split_hl(const float* __restrict__ in, u16* __restrict__ hi,
                         u16* __restrict__ lo, int n) {
  int i = blockIdx.x * 256 + threadIdx.x;
  if (i < n) {
    float v = in[i];
    u16 h = f2bf(v);
    hi[i] = h;
    lo[i] = f2bf(v - bf2f(h));
  }
}

__global__ void embed_split(const int* __restrict__ x, const float* __restrict__ emb,
                            u16* __restrict__ hi, u16* __restrict__ lo) {
  int gid = blockIdx.x * 256 + threadIdx.x;   // 4096*512 total
  int bt = gid >> 9, d = gid & 511;
  float v = emb[(size_t)x[bt] * 512 + d];
  u16 h = f2bf(v);
  hi[gid] = h;
  lo[gid] = f2bf(v - bf2f(h));
}

// Pack Whh into per-lane fp8 MFMA B-fragment order (e4m3, OCP) AND write the
// bf16 quantization residual dW = W - dequant(W_q) in row-major [1024][256]
// per (lyr,dir) for the correction GEMM.
// tid = ((((((lyr*2+dir)*8+W)*4+g)*2+ni)*8+kt)*64+lane)*2+dw   (262,144 total)
// weight row = g*256 + W*32 + ni*16 + (lane&15), k = kt*32 + (lane>>4)*8 + dw*4 + 0..3
__global__ void lstm_wpack_fp8(const float* __restrict__ Whh, u32* __restrict__ wp,
                               u16* __restrict__ dW) {
  int tid = blockIdx.x * 256 + threadIdx.x;
  int dw   = tid & 1;
  int lane = (tid >> 1) & 63;
  int kt   = (tid >> 7) & 7;
  int ni   = (tid >> 10) & 1;
  int g    = (tid >> 11) & 3;
  int W    = (tid >> 13) & 7;
  int dir  = (tid >> 16) & 1;
  int lyr  = (tid >> 17) & 1;
  int row = g * 256 + W * 32 + ni * 16 + (lane & 15);
  int k   = kt * 32 + (lane >> 4) * 8 + dw * 4;
  int ld = lyr * 2 + dir;
  const float* src = Whh + (((size_t)ld * 1024 + row) * 256);
  u32 v = __builtin_amdgcn_cvt_pk_fp8_f32(src[k], src[k + 1], 0, 0);
  v = __builtin_amdgcn_cvt_pk_fp8_f32(src[k + 2], src[k + 3], v, 1);
  wp[tid] = v;
  u16* dst = dW + ((size_t)ld * 1024 + row) * 256 + k;
  dst[0] = f2bf(src[k]     - __builtin_amdgcn_cvt_f32_fp8((int)v, 0));
  dst[1] = f2bf(src[k + 1] - __builtin_amdgcn_cvt_f32_fp8((int)v, 1));
  dst[2] = f2bf(src[k + 2] - __builtin_amdgcn_cvt_f32_fp8((int)v, 2));
  dst[3] = f2bf(src[k + 3] - __builtin_amdgcn_cvt_f32_fp8((int)v, 3));
}

// residual add: a (f32) + (bHi+bLo reconstructed) -> hi/lo bf16
__global__ void resadd_split(const float* __restrict__ a, const u16* __restrict__ bHi,
                             const u16* __restrict__ bLo,
                             u16* __restrict__ hi, u16* __restrict__ lo, int n) {
  int i = blockIdx.x * 256 + threadIdx.x;
  if (i < n) {
    float v = a[i] + bf2f(bHi[i]) + bf2f(bLo[i]);
    u16 h = f2bf(v);
    hi[i] = h;
    lo[i] = f2bf(v - bf2f(h));
  }
}

// ---------------- bf16 MFMA GEMM: C = A * B^T + bias ----------------
// A: M x K rows stride lda (hi [+lo if ALO] bf16), B: N x K (bf16 hi [+lo if BLO])
// Passes: AhBh (+ AlBh if ALO) (+ AhBl if BLO).
// XSWZ: write C in lstm per-lane frag order (f32 if !WHL, bf16 via Chi if WHL).
template<int RELU, int WF32, int WHL, int XSWZ, int BLO, int ALO>
__global__ __launch_bounds__(256) void gemm_x3(
    const u16* __restrict__ Ahi, const u16* __restrict__ Alo,
    const u16* __restrict__ Bhi, const u16* __restrict__ Blo,
    const float* __restrict__ bias,
    float* __restrict__ Cf, u16* __restrict__ Chi, u16* __restrict__ Clo,
    int M, int N, int Kd, int lda)
{
  __shared__ u16 As_hi[128][40], Bs_hi[128][40];
  __shared__ u16 As_lo[ALO ? 128 : 1][ALO ? 40 : 1];
  __shared__ u16 Bs_lo[BLO ? 128 : 1][BLO ? 40 : 1];
  int t = threadIdx.x;
  int bm = blockIdx.x * 128, bn = blockIdx.y * 128;
  int l = t & 63, wid = t >> 6;
  int wy = wid >> 1, wx = wid & 1;
  f32x4 acc[4][4];
#pragma unroll
  for (int i = 0; i < 4; i++)
#pragma unroll
    for (int j = 0; j < 4; j++) acc[i][j] = (f32x4){0.f, 0.f, 0.f, 0.f};

  for (int kt = 0; kt < Kd; kt += 32) {
    __syncthreads();
#pragma unroll
    for (int cc = 0; cc < 2; cc++) {
      int c = t + cc * 256;
      int row = c >> 2, k8 = (c & 3) << 3;
      *(uint4*)&As_hi[row][k8] = *(const uint4*)(Ahi + (size_t)(bm + row) * lda + kt + k8);
      if (ALO)
        *(uint4*)&As_lo[row][k8] = *(const uint4*)(Alo + (size_t)(bm + row) * lda + kt + k8);
      *(uint4*)&Bs_hi[row][k8] = *(const uint4*)(Bhi + (size_t)(bn + row) * Kd + kt + k8);
      if (BLO)
        *(uint4*)&Bs_lo[row][k8] = *(const uint4*)(Blo + (size_t)(bn + row) * Kd + kt + k8);
    }
    __syncthreads();
    bf16x8 bh[4], bl[4];
    int k8 = (l >> 4) << 3;
#pragma unroll
    for (int ni = 0; ni < 4; ni++) {
      int r = wx * 64 + ni * 16 + (l & 15);
      bh[ni] = *(const bf16x8*)&Bs_hi[r][k8];
      if (BLO) bl[ni] = *(const bf16x8*)&Bs_lo[r][k8];
    }
#pragma unroll
    for (int mi = 0; mi < 4; mi++) {
      int r = wy * 64 + mi * 16 + (l & 15);
      bf16x8 ah = *(const bf16x8*)&As_hi[r][k8];
      bf16x8 al;
      if (ALO) al = *(const bf16x8*)&As_lo[r][k8];
#pragma unroll
      for (int ni = 0; ni < 4; ni++) {
        acc[mi][ni] = __builtin_amdgcn_mfma_f32_16x16x32_bf16(ah, bh[ni], acc[mi][ni], 0, 0, 0);
        if (ALO)
          acc[mi][ni] = __builtin_amdgcn_mfma_f32_16x16x32_bf16(al, bh[ni], acc[mi][ni], 0, 0, 0);
        if (BLO)
          acc[mi][ni] = __builtin_amdgcn_mfma_f32_16x16x32_bf16(ah, bl[ni], acc[mi][ni], 0, 0, 0);
      }
    }
  }
#pragma unroll
  for (int ni = 0; ni < 4; ni++) {
    int col = bn + wx * 64 + ni * 16 + (l & 15);
    float bv = bias ? bias[col] : 0.f;
#pragma unroll
    for (int mi = 0; mi < 4; mi++) {
#pragma unroll
      for (int r = 0; r < 4; r++) {
        int row = bm + wy * 64 + mi * 16 + (l >> 4) * 4 + r;
        float v = acc[mi][ni][r] + bv;
        if (RELU) v = fmaxf(v, 0.f);
        if (XSWZ) {
          // row = b*256 + t; col = gate-row (g*256 + u8), u8 = W*32 + ni*16 + uu
          int tt = row & 255, b = row >> 8;
          int g = col >> 8, u8 = col & 255;
          int Wv = u8 >> 5, nn = (u8 >> 4) & 1, uu = u8 & 15;
          int lane = ((b >> 2) << 4) | uu;
          size_t o = ((((((size_t)tt * 8 + Wv) * 4 + g) * 2 + nn) * 64) + lane) * 4 + (b & 3);
          if (WHL) Chi[o] = f2bf(v);
          else Cf[o] = v;
        } else {
          size_t o = (size_t)row * N + col;
          if (WF32) Cf[o] = v;
          if (WHL) { u16 h = f2bf(v); Chi[o] = h; Clo[o] = f2bf(v - bf2f(h)); }
        }
      }
    }
  }
}

// ---------------- LSTM recurrence: 512 threads (8 waves) per direction ----------------
// Wave W owns all 4 gates of units [W*32,(W+1)*32) (2 n-tiles of 16).
// Whh resident in VGPRs as fp8 e4m3 B-frags: 4g x 2ni x 8kt = 128 VGPRs.
// 2 waves/SIMD -> 256-VGPR budget. xw folded into MFMA C-init.
// PASS 1: single-fp8 h exchange, writes approximate trajectory h1 (bf16).
// PASS 2: acc init = xw + corr_prev (corr = dW @ h1, cancels fp8 weight error);
//         h exchange fp8 hi + fp8 residual; writes hi/lo bf16 outputs.
template<int PASS>
__global__ __launch_bounds__(512, 2) void lstm_rec5(
    const u32* __restrict__ wpack_l,
    const float* __restrict__ xwsw_f, const float* __restrict__ xwsw_b,
    const u16* __restrict__ corr_f, const u16* __restrict__ corr_b,
    u16* __restrict__ h1out,
    u16* __restrict__ out_hi, u16* __restrict__ out_lo)
{
  int dir = blockIdx.x;
  int tid = threadIdx.x;
  int W = tid >> 6, l = tid & 63;
  int bb  = l & 15;            // A-frag row (batch) for LDS reads
  int mb  = (l >> 4) * 4;      // C-frag batch base
  const float* xw = dir ? xwsw_b : xwsw_f;
  const u16* corr = dir ? corr_b : corr_f;

  // resident fp8 weight fragments: wf[g][ni][kt]  (128 VGPRs)
  long wf[4][2][8];
  {
    const long* wp64 = (const long*)wpack_l;
#pragma unroll
    for (int g = 0; g < 4; g++)
#pragma unroll
      for (int ni = 0; ni < 2; ni++)
#pragma unroll
        for (int kt = 0; kt < 8; kt++)
          wf[g][ni][kt] = wp64[(size_t)((((dir * 8 + W) * 4 + g) * 2 + ni) * 8 + kt) * 64 + l];
  }

  __shared__ unsigned char hH8[2][16][256];
  __shared__ unsigned char hL8[PASS == 2 ? 2 : 1][PASS == 2 ? 16 : 1][PASS == 2 ? 256 : 1];

  f32x4 cst[2] = {(f32x4){0.f,0.f,0.f,0.f}, (f32x4){0.f,0.f,0.f,0.f}};

  for (int s = 0; s < 256; s++) {
    int tpos = dir ? (255 - s) : s;
    int cb = s & 1, pb = cb ^ 1;

    // acc init = xw (+ corr_prev for PASS2)
    const float* xb = xw + ((size_t)tpos * 8 + W) * 2048;
    f32x4 acc[4][2];
#pragma unroll
    for (int g = 0; g < 4; g++)
#pragma unroll
      for (int ni = 0; ni < 2; ni++)
        acc[g][ni] = *(const f32x4*)(xb + (g * 2 + ni) * 256 + l * 4);

    if (PASS == 2 && s > 0) {
      int tprev = dir ? (tpos + 1) : (tpos - 1);
      const u16* cbp = corr + ((size_t)tprev * 8 + W) * 2048;
#pragma unroll
      for (int g = 0; g < 4; g++)
#pragma unroll
        for (int ni = 0; ni < 2; ni++) {
          u16x4 cv = *(const u16x4*)(cbp + (g * 2 + ni) * 256 + l * 4);
#pragma unroll
          for (int r = 0; r < 4; r++) acc[g][ni][r] += bf2f(cv[r]);
        }
    }

    if (s > 0) {
#pragma unroll
      for (int kt = 0; kt < 8; kt++) {
        int off = (((kt * 4 + (l >> 4)) ^ (bb & 7)) << 3);
        long ah = *(const long*)&hH8[pb][bb][off];
#pragma unroll
        for (int g = 0; g < 4; g++)
#pragma unroll
          for (int ni = 0; ni < 2; ni++)
            acc[g][ni] = __builtin_amdgcn_mfma_f32_16x16x32_fp8_fp8(ah, wf[g][ni][kt], acc[g][ni], 0, 0, 0);
        if (PASS == 2) {
          long al = *(const long*)&hL8[pb][bb][off];
#pragma unroll
          for (int g = 0; g < 4; g++)
#pragma unroll
            for (int ni = 0; ni < 2; ni++)
              acc[g][ni] = __builtin_amdgcn_mfma_f32_16x16x32_fp8_fp8(al, wf[g][ni][kt], acc[g][ni], 0, 0, 0);
        }
      }
    }

    // gates in registers: lane has all 4 gates for 2 units x 4 batches
#pragma unroll
    for (int ni = 0; ni < 2; ni++) {
      int u = W * 32 + ni * 16 + (l & 15);
#pragma unroll
      for (int r = 0; r < 4; r++) {
        float gi = acc[0][ni][r];
        float gf = acc[1][ni][r];
        float gg = acc[2][ni][r];
        float go = acc[3][ni][r];
        float si = 1.f / (1.f + __expf(-gi));
        float sf = 1.f / (1.f + __expf(-gf));
        float so = 1.f / (1.f + __expf(-go));
        float tg = 1.f - 2.f / (__expf(2.f * gg) + 1.f);
        float c = sf * cst[ni][r] + si * tg;
        cst[ni][r] = c;
        float th = 1.f - 2.f / (__expf(2.f * c) + 1.f);
        float h = so * th;

        int b = mb + r;
        int idx = (((u >> 3) ^ (b & 7)) << 3) + (u & 7);
        u32 ph = __builtin_amdgcn_cvt_pk_fp8_f32(h, h, 0, 0);
        hH8[cb][b][idx] = (unsigned char)(ph & 0xFF);
        if (PASS == 2) {
          float fh = __builtin_amdgcn_cvt_f32_fp8((int)ph, 0);
          u32 pl = __builtin_amdgcn_cvt_pk_fp8_f32(h - fh, h - fh, 0, 0);
          hL8[cb][b][idx] = (unsigned char)(pl & 0xFF);
        }

        size_t oo = (((size_t)b * 256 + tpos) * 512) + dir * 256 + u;
        if (PASS == 1) {
          h1out[oo] = f2bf(h);
        } else {
          u16 hb = f2bf(h);
          out_hi[oo] = hb;
          out_lo[oo] = f2bf(h - bf2f(hb));
        }
      }
    }
    __syncthreads();
  }
}

// ---------------- final small GEMM (fp32 exact): em = h256 * out_W^T + out_b
__global__ __launch_bounds__(256) void out_gemm(const float* __restrict__ h,
                                                const float* __restrict__ Wo,
                                                const float* __restrict__ bo,
                                                float* __restrict__ em)
{
  int t = threadIdx.x;
  if (t >= 160) return;
  int r = t / 20, j = t - r * 20;
  int bt = blockIdx.x * 8 + r;
  const float* hr = h + (size_t)bt * 256;
  const float* wr = Wo + j * 256;
  float acc = 0.f;
#pragma unroll 4
  for (int k = 0; k < 256; k++) acc += hr[k] * wr[k];
  em[(size_t)bt * 20 + j] = acc + bo[j];
}

// ---------------- Viterbi ----------------
__global__ __launch_bounds__(192) void viterbi(const float* __restrict__ em,
                                               const float* __restrict__ cstart,
                                               const float* __restrict__ cend,
                                               const float* __restrict__ ctrans,
                                               float* __restrict__ tago)
{
  __shared__ float sc[8][20];
  __shared__ float tl[400];
  __shared__ unsigned char hist[255][8][20];
  int t = threadIdx.x;
  for (int i = t; i < 400; i += 192) tl[i] = ctrans[i];
  int bl = t / 20, j = t - bl * 20;
  bool act = (t < 160);
  int b = blockIdx.x * 8 + bl;
  if (act) sc[bl][j] = cstart[j] + em[((size_t)b * 256) * 20 + j];
  __syncthreads();
  for (int step = 1; step < 256; step++) {
    float best = -1e30f; int bi = 0;
    if (act) {
      best = sc[bl][0] + tl[j]; bi = 0;
#pragma unroll
      for (int i = 1; i < 20; i++) {
        float v = sc[bl][i] + tl[i * 20 + j];
        if (v > best) { best = v; bi = i; }
      }
      hist[step - 1][bl][j] = (unsigned char)bi;
    }
    __syncthreads();
    if (act) sc[bl][j] = best + em[((size_t)b * 256 + step) * 20 + j];
    __syncthreads();
  }
  if (act && j == 0) {
    float best = sc[bl][0] + cend[0]; int bj = 0;
    for (int i = 1; i < 20; i++) {
      float v = sc[bl][i] + cend[i];
      if (v > best) { best = v; bj = i; }
    }
    int tag = bj;
    tago[(size_t)b * 256 + 255] = (float)tag;
    for (int step = 254; step >= 0; step--) {
      tag = hist[step][bl][tag];
      tago[(size_t)b * 256 + step] = (float)tag;
    }
  }
}

// ---------------- launch ----------------
extern "C" void kernel_launch(void* const* d_in, const int* in_sizes, int n_in,
                              void* d_out, int out_size, void* d_ws, size_t ws_size,
                              hipStream_t stream)
{
  const int*   x   = (const int*)  d_in[0];
  const float* emb = (const float*)d_in[1];
  const float* Wih = (const float*)d_in[2];
  const float* Whh = (const float*)d_in[3];
  const float* lb  = (const float*)d_in[4];
  const float* fW1 = (const float*)d_in[5];
  const float* fb1 = (const float*)d_in[6];
  const float* fW2 = (const float*)d_in[7];
  const float* fb2 = (const float*)d_in[8];
  const float* foW = (const float*)d_in[9];
  const float* fob = (const float*)d_in[10];
  const float* oW  = (const float*)d_in[11];
  const float* ob  = (const float*)d_in[12];
  const float* cst = (const float*)d_in[13];
  const float* cen = (const float*)d_in[14];
  const float* ctr = (const float*)d_in[15];

  const size_t MB = 1u << 20;
  if (ws_size < 95 * MB) return;
  char* ws = (char*)d_ws;

  u16* embHi = (u16*)(ws + 0 * MB);
  u16* embLo = (u16*)(ws + 4 * MB);
  u16* l1Hi  = (u16*)(ws + 8 * MB);
  u16* l1Lo  = (u16*)(ws + 12 * MB);
  u16* l2Hi  = (u16*)(ws + 16 * MB);
  u16* l2Lo  = (u16*)(ws + 20 * MB);
  float* xwF = (float*)(ws + 24 * MB);   // swizzled xw fwd (16 MB)
  float* xwB = (float*)(ws + 40 * MB);   // swizzled xw bwd (16 MB)
  u16* corrF = (u16*)(ws + 56 * MB);     // swizzled corr fwd (bf16, 8 MB)
  u16* corrB = (u16*)(ws + 64 * MB);     // swizzled corr bwd (bf16, 8 MB)
  u16* h1    = (u16*)(ws + 72 * MB);     // pass-1 trajectory [b][t][512] bf16 (4 MB)
  u32* wpck  = (u32*)(ws + 76 * MB);     // fp8 packed Whh (1 MB; 131072 u32/layer)
  u16* dW    = (u16*)(ws + 77 * MB);     // bf16 residual W - W_q (2 MB; [l,d][1024][256])
  u16* wihHi = (u16*)(ws + 79 * MB);
  u16* wihLo = (u16*)(ws + 83 * MB);
  u16* fw1Hi = (u16*)(ws + 87 * MB);
  u16* fw1Lo = (u16*)(ws + 88 * MB);
  u16* fw2Hi = (u16*)(ws + 89 * MB);
  u16* fw2Lo = (u16*)(ws + 90 * MB);
  u16* ffoHi = (u16*)(ws + 91 * MB);
  u16* ffoLo = (u16*)(ws + 91 * MB + 512 * 1024);
  // aliases into xw regions (free after the recurrent layers)
  u16* t1Hi = (u16*)xwF;
  u16* t1Lo = (u16*)((char*)xwF + 4 * MB);
  u16* t2Hi = (u16*)xwB;
  u16* t2Lo = (u16*)((char*)xwB + 4 * MB);
  float* h2F = (float*)((char*)xwB + 8 * MB);
  u16* sumHi = (u16*)((char*)xwF + 8 * MB);
  u16* sumLo = (u16*)((char*)xwF + 12 * MB);
  float* h256F = (float*)xwF;

  float* em   = (float*)d_out;
  float* tago = (float*)d_out + 81920;

  dim3 blk(256);

  // weight prep
  split_hl<<<8192, blk, 0, stream>>>(Wih, wihHi, wihLo, 4 * 1024 * 512);
  split_hl<<<2048, blk, 0, stream>>>(fW1, fw1Hi, fw1Lo, 2 * 512 * 512);
  split_hl<<<2048, blk, 0, stream>>>(fW2, fw2Hi, fw2Lo, 2 * 512 * 512);
  split_hl<<<512,  blk, 0, stream>>>(foW, ffoHi, ffoLo, 256 * 512);
  lstm_wpack_fp8<<<1024, blk, 0, stream>>>(Whh, wpck, dW);
  embed_split<<<8192, blk, 0, stream>>>(x, emb, embHi, embLo);

  for (int lyr = 0; lyr < 2; lyr++) {
    const u16* inHi = lyr ? l1Hi : embHi;
    const u16* inLo = lyr ? l1Lo : embLo;
    u16* outHi = lyr ? l2Hi : l1Hi;
    u16* outLo = lyr ? l2Lo : l1Lo;
    const u32* wp_l = wpck + lyr * 131072;

    // xw GEMMs (write swizzled f32)
    gemm_x3<0,1,0,1,0,1><<<dim3(32, 8), blk, 0, stream>>>(inHi, inLo,
        wihHi + (lyr * 2 + 0) * 524288, wihLo + (lyr * 2 + 0) * 524288,
        lb + (lyr * 2 + 0) * 1024, xwF, nullptr, nullptr, 4096, 1024, 512, 512);
    gemm_x3<0,1,0,1,0,1><<<dim3(32, 8), blk, 0, stream>>>(inHi, inLo,
        wihHi + (lyr * 2 + 1) * 524288, wihLo + (lyr * 2 + 1) * 524288,
        lb + (lyr * 2 + 1) * 1024, xwB, nullptr, nullptr, 4096, 1024, 512, 512);

    // pass 1: fp8 recurrence -> approximate trajectory h1
    lstm_rec5<1><<<2, dim3(512), 0, stream>>>(wp_l, xwF, xwB,
        nullptr, nullptr, h1, nullptr, nullptr);

    // correction GEMMs: corr = h1 @ dW^T (bf16 single-pass, swizzled bf16 out)
    gemm_x3<0,0,1,1,0,0><<<dim3(32, 8), blk, 0, stream>>>(h1 + 0, h1,
        dW + (size_t)(lyr * 2 + 0) * 262144, nullptr, nullptr,
        nullptr, corrF, nullptr, 4096, 1024, 256, 512);
    gemm_x3<0,0,1,1,0,0><<<dim3(32, 8), blk, 0, stream>>>(h1 + 256, h1,
        dW + (size_t)(lyr * 2 + 1) * 262144, nullptr, nullptr,
        nullptr, corrB, nullptr, 4096, 1024, 256, 512);

    // pass 2: corrected recurrence -> bf16 hi/lo outputs
    lstm_rec5<2><<<2, dim3(512), 0, stream>>>(wp_l, xwF, xwB,
        corrF, corrB, nullptr, outHi, outLo);
  }

  // FF stack
  gemm_x3<1,0,1,0,0,1><<<dim3(32, 4), blk, 0, stream>>>(l2Hi, l2Lo,
      fw1Hi + 0, fw1Lo + 0, fb1 + 0, nullptr, t1Hi, t1Lo, 4096, 512, 512, 512);
  gemm_x3<0,0,1,0,0,1><<<dim3(32, 4), blk, 0, stream>>>(t1Hi, t1Lo,
      fw2Hi + 0, fw2Lo + 0, fb2 + 0, nullptr, t2Hi, t2Lo, 4096, 512, 512, 512);
  gemm_x3<1,0,1,0,0,1><<<dim3(32, 4), blk, 0, stream>>>(t2Hi, t2Lo,
      fw1Hi + 262144, fw1Lo + 262144, fb1 + 512, nullptr, t1Hi, t1Lo, 4096, 512, 512, 512);
  gemm_x3<0,1,0,0,0,1><<<dim3(32, 4), blk, 0, stream>>>(t1Hi, t1Lo,
      fw2Hi + 262144, fw2Lo + 262144, fb2 + 512, h2F, nullptr, nullptr, 4096, 512, 512, 512);
  resadd_split<<<8192, blk, 0, stream>>>(h2F, l2Hi, l2Lo, sumHi, sumLo, 4096 * 512);
  gemm_x3<0,1,0,0,0,1><<<dim3(32, 2), blk, 0, stream>>>(sumHi, sumLo,
      ffoHi, ffoLo, fob, h256F, nullptr, nullptr, 4096, 256, 512, 512);

  out_gemm<<<512, blk, 0, stream>>>(h256F, oW, ob, em);
  viterbi<<<2, dim3(192), 0, stream>>>(em, cst, cen, ctr, tago);
}